// Round 4
// baseline (73.274 us; speedup 1.0000x reference)
//
#include <hip/hip_runtime.h>
#include <math.h>

static constexpr int NA = 9;
static constexpr int NH = 128;
static constexpr int NW = 128;
static constexpr int NC = 4;
static constexpr int CH = 6 + NC;      // 10 channels
static constexpr int TCOLS = 13 + NC;  // 17 target columns
static constexpr float SCALE_INV = 1.0f / 16.0f;
static constexpr int NBG = 1024;       // background-streaming blocks
static constexpr int SCAN_STRIDE = 16; // floats per scan-block partial record

// ANCHORS_PX / 16
__constant__ float c_aw[NA] = {1.f, 2.f, 4.f, 8.f, 16.f, 2.f, 4.f, 8.f, 4.f};
__constant__ float c_ah[NA] = {1.f, 2.f, 4.f, 8.f, 16.f, 4.f, 2.f, 4.f, 8.f};

// scan partial slots: 0 corrNum, 1 corrDen, 2 maskCnt, 3 lx, 4 ly, 5 lw,
// 6 lh, 7 lcls, 8 lconfM, 9 nGT, 10 nCor
static constexpr int NSLOT = 11;

__device__ __forceinline__ float bcef(float x, float z) {
    return fmaxf(x, 0.f) - x * z + log1pf(expf(-fabsf(x)));
}
__device__ __forceinline__ float invtanh(float y) {
    if (y <= -1.f) return -2.f;
    if (y >= 1.f) return 2.f;
    return 0.5f * logf((1.f + y) / (1.f - y));
}
__device__ __forceinline__ float wredf(float v) {
#pragma unroll
    for (int o = 32; o; o >>= 1) v += __shfl_down(v, o, 64);
    return v;
}
__device__ __forceinline__ double wredd(double v) {
#pragma unroll
    for (int o = 32; o; o >>= 1) v += __shfl_down(v, o, 64);
    return v;
}

// Fused kernel. Blocks [0, nB): scan role (one batch each). Blocks
// [nB, nB+NBG): background conf-BCE streaming. Last block to finish
// (device-scope done counter) reduces all partials and writes out.
__global__ __launch_bounds__(256) void k_all(
    const float* __restrict__ pred, const float* __restrict__ tgt,
    const int* __restrict__ tsz, float* __restrict__ scanPart,
    float2* __restrict__ bgPart, unsigned int* __restrict__ doneCtr,
    float* __restrict__ out, int nB, int T, int nCells, double totalCells) {
    const int tid = threadIdx.x;
    const int lane = tid & 63;
    const int wave = tid >> 6;
    const int nBlocksTotal = nB + NBG;

    __shared__ int sPack[64];
    __shared__ float sAccW[4][NSLOT];
    __shared__ float sRed[2][4];
    __shared__ int sFlag;

    if ((int)blockIdx.x < nB) {
        // ---------------- scan role: one wave-shuffled batch ----------------
        const int b = blockIdx.x;
        const int ts = tsz[b];
        if (tid < 64) sPack[tid] = 0;
        __syncthreads();

        float rTx = 0.f, rTy = 0.f, rTw = 0.f, rTh = 0.f;
        int rTl = 0;
        float fGT = 0.f, fCor = 0.f;

        // ---- Phase A: lane t <- target t (T <= 64; harness T = 50) ----
        if (wave == 0 && lane < T) {
            const int t = lane;
            const float* row = tgt + (size_t)(b * T + t) * TCOLS;
            float gx = row[0] * SCALE_INV, gy = row[1] * SCALE_INV;
            float gh = row[3] * SCALE_INV, gw = row[4] * SCALE_INV;
            int valid = (t < ts) && (gw != 0.f) && (gh != 0.f);
            int gi = (int)gx; gi = gi < 0 ? 0 : (gi > NW - 1 ? NW - 1 : gi);
            int gj = (int)gy; gj = gj < 0 ? 0 : (gj > NH - 1 ? NH - 1 : gj);

            float bestIou = -1.f; int best = 0; int ign = 0;
#pragma unroll
            for (int a = 0; a < NA; a++) {
                float aw = c_aw[a], ah = c_ah[a];
                float inter = (fminf(gw, aw) + 1.f) * (fminf(gh, ah) + 1.f);
                float uni = (gw + 1.f) * (gh + 1.f) + (aw + 1.f) * (ah + 1.f) - inter + 1e-16f;
                float iou = inter / uni;
                if (iou > 0.5f) ign |= (1 << a);
                if (iou > bestIou) { bestIou = iou; best = a; }
            }
            sPack[t] = (valid ? 1 : 0) | (best << 1) | (ign << 5) | ((gj * NW + gi) << 14);
            rTx = invtanh(gx - ((float)gi + 0.5f));
            rTy = invtanh(gy - ((float)gj + 0.5f));
            rTw = logf(gw / c_aw[best] + 1e-16f);
            rTh = logf(gh / c_ah[best] + 1e-16f);

            float cc0 = row[13], cc1 = row[14], cc2 = row[15], cc3 = row[16];
            rTl = 0; float cmax = cc0;
            if (cc1 > cmax) { cmax = cc1; rTl = 1; }
            if (cc2 > cmax) { cmax = cc2; rTl = 2; }
            if (cc3 > cmax) { cmax = cc3; rTl = 3; }

            if (valid) {
                fGT = 1.f;
                const float* p = pred + ((((size_t)b * NA + best) * NH + gj) * NW + gi) * CH;
                float p0 = p[0];
                float px = tanhf(p[1]) + 0.5f + (float)gi;
                float py = tanhf(p[2]) + 0.5f + (float)gj;
                float pw = expf(p[5]) * c_aw[best];
                float ph = expf(p[4]) * c_ah[best];
                float b1x1 = gx - gw, b1x2 = gx + gw, b1y1 = gy - gh, b1y2 = gy + gh;
                float b2x1 = px - pw, b2x2 = px + pw, b2y1 = py - ph, b2y2 = py + ph;
                float iw = fmaxf(fminf(b1x2, b2x2) - fmaxf(b1x1, b2x1) + 1.f, 0.f);
                float ih = fmaxf(fminf(b1y2, b2y2) - fmaxf(b1y1, b2y1) + 1.f, 0.f);
                float inter = iw * ih;
                float a1 = (b1x2 - b1x1 + 1.f) * (b1y2 - b1y1 + 1.f);
                float a2 = (b2x2 - b2x1 + 1.f) * (b2y2 - b2y1 + 1.f);
                float iou = inter / (a1 + a2 - inter + 1e-16f);
                float q0 = p[6], q1 = p[7], q2 = p[8], q3 = p[9];
                int pl = 0; float qm = q0;
                if (q1 > qm) { qm = q1; pl = 1; }
                if (q2 > qm) { qm = q2; pl = 2; }
                if (q3 > qm) { qm = q3; pl = 3; }
                if (iou > 0.5f && pl == rTl && p0 > 0.f) fCor = 1.f;
            }
        }
        __syncthreads();

        const int pk = (lane < T) ? sPack[lane] : 0;

        // ---- Phase C1: winner-per-(cell,anchor) via register shuffles.
        // pri = 2t+1 for best-touch, 2t for ignore-touch (reference write
        // order). Anchors distributed across the 4 waves. ----
        float corrNum = 0.f, corrDen = 0.f, lconfM = 0.f, maskCnt = 0.f;
        for (int a = wave; a < NA; a += 4) {
            int valid = pk & 1;
            int myCell = pk >> 14;
            int myBest = (pk >> 1) & 0xF;
            int isBest = valid && (myBest == a);
            int isIgn = valid && !isBest && ((pk >> (5 + a)) & 1);
            int myPri = isBest ? (2 * lane + 1) : (isIgn ? (2 * lane) : -2);
            int maxPri = -1, anyBest = 0;
            for (int u = 0; u < T; u++) {
                int q = __shfl(pk, u, 64);
                int same = (q & 1) && ((q >> 14) == myCell);
                int qb = (q >> 1) & 0xF;
                int qBest = same && (qb == a);
                int qIgn = same && (qb != a) && ((q >> (5 + a)) & 1);
                int pri = qBest ? (2 * u + 1) : (qIgn ? (2 * u) : -1);
                maxPri = max(maxPri, pri);
                anyBest |= qBest;
            }
            if (valid && myPri >= 0 && myPri == maxPri) {
                int gj = myCell >> 7, gi = myCell & (NW - 1);
                float conf = pred[((((size_t)b * NA + a) * NH + gj) * NW + gi) * CH];
                float bce0 = bcef(conf, 0.f);
                if (anyBest) {                    // masked: mask=1, tconf=1
                    float cm = (maxPri & 1) ? 1.f : 0.f;
                    float cmf = cm - 1.f;         // 0 or -1
                    float bce1 = bcef(conf, 1.f);
                    corrNum += bce1 * cmf - bce0;
                    corrDen += cmf - 1.f;
                    lconfM += bce1;
                    maskCnt += 1.f;
                } else {                          // ignore-only: cmf = 0
                    corrNum -= bce0;
                    corrDen -= 1.f;
                }
            }
        }

        // ---- Phase C2: last valid writer per (cell,best): coord + cls ----
        float lx = 0.f, ly = 0.f, lw = 0.f, lh = 0.f, lcls = 0.f;
        if (wave == 0) {
            int valid = pk & 1;
            int myCell = pk >> 14, myBest = (pk >> 1) & 0xF;
            int isLast = valid;
            for (int u = 0; u < T; u++) {
                int q = __shfl(pk, u, 64);
                int later = (u > lane) && (q & 1) && ((q >> 14) == myCell) &&
                            (((q >> 1) & 0xF) == myBest);
                isLast &= !later;
            }
            if (isLast) {
                int gj = myCell >> 7, gi = myCell & (NW - 1);
                const float* pp = pred + ((((size_t)b * NA + myBest) * NH + gj) * NW + gi) * CH;
                float dx = pp[1] - rTx, dy = pp[2] - rTy;
                float dw = pp[5] - rTw, dh = pp[4] - rTh;
                lx = dx * dx; ly = dy * dy; lw = dw * dw; lh = dh * dh;
                float q0 = pp[6], q1 = pp[7], q2 = pp[8], q3 = pp[9];
                float m = fmaxf(fmaxf(q0, q1), fmaxf(q2, q3));
                float lse = m + logf(expf(q0 - m) + expf(q1 - m) + expf(q2 - m) + expf(q3 - m));
                lcls = lse - pp[6 + rTl];
            }
        }

        // deterministic per-wave partials
        float v;
        v = wredf(corrNum); if (lane == 0) sAccW[wave][0] = v;
        v = wredf(corrDen); if (lane == 0) sAccW[wave][1] = v;
        v = wredf(maskCnt); if (lane == 0) sAccW[wave][2] = v;
        v = wredf(lx);      if (lane == 0) sAccW[wave][3] = v;
        v = wredf(ly);      if (lane == 0) sAccW[wave][4] = v;
        v = wredf(lw);      if (lane == 0) sAccW[wave][5] = v;
        v = wredf(lh);      if (lane == 0) sAccW[wave][6] = v;
        v = wredf(lcls);    if (lane == 0) sAccW[wave][7] = v;
        v = wredf(lconfM);  if (lane == 0) sAccW[wave][8] = v;
        v = wredf(fGT);     if (lane == 0) sAccW[wave][9] = v;
        v = wredf(fCor);    if (lane == 0) sAccW[wave][10] = v;
        __syncthreads();
        if (tid < NSLOT) {
            float s = sAccW[0][tid] + sAccW[1][tid] + sAccW[2][tid] + sAccW[3][tid];
            scanPart[b * SCAN_STRIDE + tid] = s;
        }
    } else {
        // ---------------- bg role: stream the conf channel ----------------
        const int bgid = blockIdx.x - nB;
        float s0 = 0.f, npos = 0.f;
        const int stride = NBG * 256;
        int c = bgid * 256 + tid;
        for (; c + 2 * stride < nCells; c += 3 * stride) {
            float c0 = pred[(size_t)c * CH];
            float c1 = pred[(size_t)(c + stride) * CH];
            float c2 = pred[(size_t)(c + 2 * stride) * CH];
            s0 += fmaxf(c0, 0.f) + log1pf(expf(-fabsf(c0)));
            s0 += fmaxf(c1, 0.f) + log1pf(expf(-fabsf(c1)));
            s0 += fmaxf(c2, 0.f) + log1pf(expf(-fabsf(c2)));
            npos += (c0 > 0.f) ? 1.f : 0.f;
            npos += (c1 > 0.f) ? 1.f : 0.f;
            npos += (c2 > 0.f) ? 1.f : 0.f;
        }
        for (; c < nCells; c += stride) {
            float cv = pred[(size_t)c * CH];
            s0 += fmaxf(cv, 0.f) + log1pf(expf(-fabsf(cv)));
            npos += (cv > 0.f) ? 1.f : 0.f;
        }
        s0 = wredf(s0); npos = wredf(npos);
        if (lane == 0) { sRed[0][wave] = s0; sRed[1][wave] = npos; }
        __syncthreads();
        if (tid == 0) {
            float a0 = sRed[0][0] + sRed[0][1] + sRed[0][2] + sRed[0][3];
            float a1 = sRed[1][0] + sRed[1][1] + sRed[1][2] + sRed[1][3];
            bgPart[bgid] = make_float2(a0, a1);
        }
    }

    // ---------------- completion rendezvous + finalize ----------------
    __syncthreads();
    if (tid == 0) {
        __threadfence();  // release partials to device scope
        unsigned int old = atomicAdd(doneCtr, 1u);
        sFlag = (old == (unsigned int)(nBlocksTotal - 1)) ? 1 : 0;
    }
    __syncthreads();
    if (sFlag) {
        __threadfence();  // acquire
        __shared__ double dR[2][4];
        __shared__ double dScan[NSLOT];
        double s0 = 0.0, np = 0.0;
        for (int i = tid; i < NBG; i += 256) {
            float2 v = bgPart[i];
            s0 += (double)v.x; np += (double)v.y;
        }
        s0 = wredd(s0); np = wredd(np);
        if (lane == 0) { dR[0][wave] = s0; dR[1][wave] = np; }
        if (tid < NSLOT) {
            double s = 0.0;
            for (int b2 = 0; b2 < nB; b2++) s += (double)scanPart[b2 * SCAN_STRIDE + tid];
            dScan[tid] = s;
        }
        __syncthreads();
        if (tid == 0) {
            double S0 = dR[0][0] + dR[0][1] + dR[0][2] + dR[0][3];
            double nProp = dR[1][0] + dR[1][1] + dR[1][2] + dR[1][3];
            double corrNum = dScan[0], corrDen = dScan[1], maskCnt = dScan[2];
            double lx = dScan[3], ly = dScan[4], lw = dScan[5], lh = dScan[6];
            double lcls = dScan[7], lconfM = dScan[8], nGT = dScan[9], nCor = dScan[10];

            double msum = fmax(maskCnt, 1.0);
            double cden = fmax(totalCells + corrDen, 1.0);
            double loss_conf = 1.25 * (S0 + corrNum) / cden + lconfM / msum;
            double lx_ = lx / msum, ly_ = ly / msum, lw_ = lw / msum, lh_ = lh / msum;
            double lcls_ = (lcls / msum) / (double)nB;
            double coord = lx_ + ly_ + lw_ + lh_;
            double loss = coord + loss_conf + lcls_;
            double recall = (nGT > 0.0) ? nCor / fmax(nGT, 1.0) : 1.0;
            double precision = (nProp > 0.0) ? nCor / fmax(nProp, 1.0) : 1.0;

            out[0] = (float)loss;
            out[1] = (float)coord;
            out[2] = (float)loss_conf;
            out[3] = (float)lcls_;
            out[4] = (float)recall;
            out[5] = (float)precision;
        }
    }
}

extern "C" void kernel_launch(void* const* d_in, const int* in_sizes, int n_in,
                              void* d_out, int out_size, void* d_ws, size_t ws_size,
                              hipStream_t stream) {
    const float* pred = (const float*)d_in[0];
    const float* tgt = (const float*)d_in[1];
    const int* tsz = (const int*)d_in[2];
    int nB = in_sizes[2];
    int T = in_sizes[1] / (nB * TCOLS);
    long long total = (long long)nB * NA * NH * NW;
    int nCells = (int)total;

    // d_ws layout: [scanPart: nB*SCAN_STRIDE floats][bgPart: NBG float2][doneCtr: u32]
    float* scanPart = (float*)d_ws;
    float2* bgPart = (float2*)((char*)d_ws + (size_t)nB * SCAN_STRIDE * sizeof(float));
    unsigned int* doneCtr =
        (unsigned int*)((char*)bgPart + (size_t)NBG * sizeof(float2));
    float* out = (float*)d_out;

    hipMemsetAsync(doneCtr, 0, sizeof(unsigned int), stream);
    hipLaunchKernelGGL(k_all, dim3(nB + NBG), dim3(256), 0, stream, pred, tgt, tsz,
                       scanPart, bgPart, doneCtr, out, nB, T, nCells, (double)total);
}

// Round 5
// 51.928 us; speedup vs baseline: 1.4111x; 1.4111x over previous
//
#include <hip/hip_runtime.h>
#include <math.h>

static constexpr int NA = 9;
static constexpr int NH = 128;
static constexpr int NW = 128;
static constexpr int NC = 4;
static constexpr int CH = 6 + NC;      // 10 channels
static constexpr int TCOLS = 13 + NC;  // 17 target columns
static constexpr float SCALE_INV = 1.0f / 16.0f;
static constexpr int NBG = 1024;       // k_bg grid
static constexpr int SCAN_STRIDE = 16; // floats per scan-block partial record

// ANCHORS_PX / 16
__constant__ float c_aw[NA] = {1.f, 2.f, 4.f, 8.f, 16.f, 2.f, 4.f, 8.f, 4.f};
__constant__ float c_ah[NA] = {1.f, 2.f, 4.f, 8.f, 16.f, 4.f, 2.f, 4.f, 8.f};

// scan partial slots: 0 corrNum, 1 corrDen, 2 maskCnt, 3 lx, 4 ly, 5 lw,
// 6 lh, 7 lcls, 8 lconfM, 9 nGT, 10 nCor
static constexpr int NSLOT = 11;

__device__ __forceinline__ float bcef(float x, float z) {
    return fmaxf(x, 0.f) - x * z + log1pf(expf(-fabsf(x)));
}
__device__ __forceinline__ float invtanh(float y) {
    if (y <= -1.f) return -2.f;
    if (y >= 1.f) return 2.f;
    return 0.5f * logf((1.f + y) / (1.f - y));
}
__device__ __forceinline__ float wredf(float v) {
#pragma unroll
    for (int o = 32; o; o >>= 1) v += __shfl_down(v, o, 64);
    return v;
}

// One block (4 waves) per batch. Phase A: lane t <- target t.
// Phase C: parallel last-writer resolution via unique priorities
// pri = 2*t + (touch-is-best ? 1 : 0)  -- the reference's write order --
// done entirely in registers with wave shuffles (no LDS serial loop).
__global__ __launch_bounds__(256) void k_scan(const float* __restrict__ pred,
                                              const float* __restrict__ tgt,
                                              const int* __restrict__ tsz,
                                              float* __restrict__ scanPart, int T) {
    const int b = blockIdx.x;
    const int tid = threadIdx.x;
    const int lane = tid & 63;
    const int wave = tid >> 6;

    __shared__ int sPack[64];
    __shared__ float sAccW[4][NSLOT];

    const int ts = tsz[b];
    if (tid < 64) sPack[tid] = 0;
    __syncthreads();

    float rTx = 0.f, rTy = 0.f, rTw = 0.f, rTh = 0.f;
    int rTl = 0;
    float fGT = 0.f, fCor = 0.f;

    // ---- Phase A: wave 0, lane t handles target t (T <= 64) ----
    if (wave == 0 && lane < T) {
        const int t = lane;
        const float* row = tgt + (size_t)(b * T + t) * TCOLS;
        float gx = row[0] * SCALE_INV, gy = row[1] * SCALE_INV;
        float gh = row[3] * SCALE_INV, gw = row[4] * SCALE_INV;
        int valid = (t < ts) && (gw != 0.f) && (gh != 0.f);
        int gi = (int)gx; gi = gi < 0 ? 0 : (gi > NW - 1 ? NW - 1 : gi);
        int gj = (int)gy; gj = gj < 0 ? 0 : (gj > NH - 1 ? NH - 1 : gj);

        float bestIou = -1.f; int best = 0; int ign = 0;
#pragma unroll
        for (int a = 0; a < NA; a++) {
            float aw = c_aw[a], ah = c_ah[a];
            float inter = (fminf(gw, aw) + 1.f) * (fminf(gh, ah) + 1.f);
            float uni = (gw + 1.f) * (gh + 1.f) + (aw + 1.f) * (ah + 1.f) - inter + 1e-16f;
            float iou = inter / uni;
            if (iou > 0.5f) ign |= (1 << a);
            if (iou > bestIou) { bestIou = iou; best = a; }
        }
        sPack[t] = (valid ? 1 : 0) | (best << 1) | (ign << 5) | ((gj * NW + gi) << 14);
        rTx = invtanh(gx - ((float)gi + 0.5f));
        rTy = invtanh(gy - ((float)gj + 0.5f));
        rTw = logf(gw / c_aw[best] + 1e-16f);
        rTh = logf(gh / c_ah[best] + 1e-16f);

        float cc0 = row[13], cc1 = row[14], cc2 = row[15], cc3 = row[16];
        rTl = 0; float cmax = cc0;
        if (cc1 > cmax) { cmax = cc1; rTl = 1; }
        if (cc2 > cmax) { cmax = cc2; rTl = 2; }
        if (cc3 > cmax) { cmax = cc3; rTl = 3; }

        if (valid) {
            fGT = 1.f;
            const float* p = pred + ((((size_t)b * NA + best) * NH + gj) * NW + gi) * CH;
            float p0 = p[0];
            float px = tanhf(p[1]) + 0.5f + (float)gi;
            float py = tanhf(p[2]) + 0.5f + (float)gj;
            float pw = expf(p[5]) * c_aw[best];
            float ph = expf(p[4]) * c_ah[best];
            float b1x1 = gx - gw, b1x2 = gx + gw, b1y1 = gy - gh, b1y2 = gy + gh;
            float b2x1 = px - pw, b2x2 = px + pw, b2y1 = py - ph, b2y2 = py + ph;
            float iw = fmaxf(fminf(b1x2, b2x2) - fmaxf(b1x1, b2x1) + 1.f, 0.f);
            float ih = fmaxf(fminf(b1y2, b2y2) - fmaxf(b1y1, b2y1) + 1.f, 0.f);
            float inter = iw * ih;
            float a1 = (b1x2 - b1x1 + 1.f) * (b1y2 - b1y1 + 1.f);
            float a2 = (b2x2 - b2x1 + 1.f) * (b2y2 - b2y1 + 1.f);
            float iou = inter / (a1 + a2 - inter + 1e-16f);
            float q0 = p[6], q1 = p[7], q2 = p[8], q3 = p[9];
            int pl = 0; float qm = q0;
            if (q1 > qm) { qm = q1; pl = 1; }
            if (q2 > qm) { qm = q2; pl = 2; }
            if (q3 > qm) { qm = q3; pl = 3; }
            if (iou > 0.5f && pl == rTl && p0 > 0.f) fCor = 1.f;
        }
    }
    __syncthreads();

    const int pk = (lane < T) ? sPack[lane] : 0;

    // ---- Phase C1: winner-per-(cell,anchor) via register shuffles.
    // Anchors distributed across the 4 waves. ----
    float corrNum = 0.f, corrDen = 0.f, lconfM = 0.f, maskCnt = 0.f;
    for (int a = wave; a < NA; a += 4) {
        int valid = pk & 1;
        int myCell = pk >> 14;
        int myBest = (pk >> 1) & 0xF;
        int isBest = valid && (myBest == a);
        int isIgn = valid && !isBest && ((pk >> (5 + a)) & 1);
        int myPri = isBest ? (2 * lane + 1) : (isIgn ? (2 * lane) : -2);
        int maxPri = -1, anyBest = 0;
        for (int u = 0; u < T; u++) {
            int q = __shfl(pk, u, 64);
            int same = (q & 1) && ((q >> 14) == myCell);
            int qb = (q >> 1) & 0xF;
            int qBest = same && (qb == a);
            int qIgn = same && (qb != a) && ((q >> (5 + a)) & 1);
            int pri = qBest ? (2 * u + 1) : (qIgn ? (2 * u) : -1);
            maxPri = max(maxPri, pri);
            anyBest |= qBest;
        }
        if (valid && myPri >= 0 && myPri == maxPri) {
            int gj = myCell >> 7, gi = myCell & (NW - 1);
            float conf = pred[((((size_t)b * NA + a) * NH + gj) * NW + gi) * CH];
            float bce0 = bcef(conf, 0.f);
            if (anyBest) {                    // masked: mask=1, tconf=1
                float cm = (maxPri & 1) ? 1.f : 0.f;
                float cmf = cm - 1.f;         // 0 or -1
                float bce1 = bcef(conf, 1.f);
                corrNum += bce1 * cmf - bce0;
                corrDen += cmf - 1.f;
                lconfM += bce1;
                maskCnt += 1.f;
            } else {                          // ignore-only: cmf = 0
                corrNum -= bce0;
                corrDen -= 1.f;
            }
        }
    }

    // ---- Phase C2: last valid writer per (cell,best): coord + cls ----
    float lx = 0.f, ly = 0.f, lw = 0.f, lh = 0.f, lcls = 0.f;
    if (wave == 0) {
        int valid = pk & 1;
        int myCell = pk >> 14, myBest = (pk >> 1) & 0xF;
        int isLast = valid;
        for (int u = 0; u < T; u++) {
            int q = __shfl(pk, u, 64);
            int later = (u > lane) && (q & 1) && ((q >> 14) == myCell) &&
                        (((q >> 1) & 0xF) == myBest);
            isLast &= !later;
        }
        if (isLast) {
            int gj = myCell >> 7, gi = myCell & (NW - 1);
            const float* pp = pred + ((((size_t)b * NA + myBest) * NH + gj) * NW + gi) * CH;
            float dx = pp[1] - rTx, dy = pp[2] - rTy;
            float dw = pp[5] - rTw, dh = pp[4] - rTh;
            lx = dx * dx; ly = dy * dy; lw = dw * dw; lh = dh * dh;
            float q0 = pp[6], q1 = pp[7], q2 = pp[8], q3 = pp[9];
            float m = fmaxf(fmaxf(q0, q1), fmaxf(q2, q3));
            float lse = m + logf(expf(q0 - m) + expf(q1 - m) + expf(q2 - m) + expf(q3 - m));
            lcls = lse - pp[6 + rTl];
        }
    }

    float v;
    v = wredf(corrNum); if (lane == 0) sAccW[wave][0] = v;
    v = wredf(corrDen); if (lane == 0) sAccW[wave][1] = v;
    v = wredf(maskCnt); if (lane == 0) sAccW[wave][2] = v;
    v = wredf(lx);      if (lane == 0) sAccW[wave][3] = v;
    v = wredf(ly);      if (lane == 0) sAccW[wave][4] = v;
    v = wredf(lw);      if (lane == 0) sAccW[wave][5] = v;
    v = wredf(lh);      if (lane == 0) sAccW[wave][6] = v;
    v = wredf(lcls);    if (lane == 0) sAccW[wave][7] = v;
    v = wredf(lconfM);  if (lane == 0) sAccW[wave][8] = v;
    v = wredf(fGT);     if (lane == 0) sAccW[wave][9] = v;
    v = wredf(fCor);    if (lane == 0) sAccW[wave][10] = v;
    __syncthreads();
    if (tid < NSLOT) {
        float s = sAccW[0][tid] + sAccW[1][tid] + sAccW[2][tid] + sAccW[3][tid];
        scanPart[b * SCAN_STRIDE + tid] = s;
    }
}

// Dense background pass: scalar loads of ONLY the conf channel (stride 10
// floats). Every 64B line contains a conf, so HBM line traffic matches a
// full stream, with minimal instruction count. One float2 partial / block.
__global__ __launch_bounds__(256) void k_bg(const float* __restrict__ pred,
                                            float2* __restrict__ bgPart, int nCells) {
    __shared__ float sdat[2][4];
    float s0 = 0.f, npos = 0.f;
    const int stride = gridDim.x * blockDim.x;
    int c = blockIdx.x * blockDim.x + threadIdx.x;
    for (; c + 2 * stride < nCells; c += 3 * stride) {
        float c0 = pred[(size_t)c * CH];
        float c1 = pred[(size_t)(c + stride) * CH];
        float c2 = pred[(size_t)(c + 2 * stride) * CH];
        s0 += fmaxf(c0, 0.f) + log1pf(expf(-fabsf(c0)));
        s0 += fmaxf(c1, 0.f) + log1pf(expf(-fabsf(c1)));
        s0 += fmaxf(c2, 0.f) + log1pf(expf(-fabsf(c2)));
        npos += (c0 > 0.f) ? 1.f : 0.f;
        npos += (c1 > 0.f) ? 1.f : 0.f;
        npos += (c2 > 0.f) ? 1.f : 0.f;
    }
    for (; c < nCells; c += stride) {
        float cv = pred[(size_t)c * CH];
        s0 += fmaxf(cv, 0.f) + log1pf(expf(-fabsf(cv)));
        npos += (cv > 0.f) ? 1.f : 0.f;
    }
    s0 = wredf(s0); npos = wredf(npos);
    int wid = threadIdx.x >> 6;
    if ((threadIdx.x & 63) == 0) { sdat[0][wid] = s0; sdat[1][wid] = npos; }
    __syncthreads();
    if (threadIdx.x == 0) {
        float a0 = sdat[0][0] + sdat[0][1] + sdat[0][2] + sdat[0][3];
        float a1 = sdat[1][0] + sdat[1][1] + sdat[1][2] + sdat[1][3];
        bgPart[blockIdx.x] = make_float2(a0, a1);
    }
}

__global__ __launch_bounds__(256) void k_fin(const float* __restrict__ scanPart,
                                             const float2* __restrict__ bgPart,
                                             float* __restrict__ out,
                                             double totalCells, int nB, int nbg) {
    __shared__ double sred[2][4];
    __shared__ double sscan[NSLOT];
    const int tid = threadIdx.x;

    double s0 = 0.0, np = 0.0;
    for (int i = tid; i < nbg; i += 256) {
        float2 v = bgPart[i];
        s0 += (double)v.x; np += (double)v.y;
    }
#pragma unroll
    for (int o = 32; o; o >>= 1) {
        s0 += __shfl_down(s0, o, 64);
        np += __shfl_down(np, o, 64);
    }
    int wid = tid >> 6;
    if ((tid & 63) == 0) { sred[0][wid] = s0; sred[1][wid] = np; }
    if (tid < NSLOT) {
        double s = 0.0;
        for (int b = 0; b < nB; b++) s += (double)scanPart[b * SCAN_STRIDE + tid];
        sscan[tid] = s;
    }
    __syncthreads();
    if (tid == 0) {
        double S0 = sred[0][0] + sred[0][1] + sred[0][2] + sred[0][3];
        double nProp = sred[1][0] + sred[1][1] + sred[1][2] + sred[1][3];
        double corrNum = sscan[0], corrDen = sscan[1], maskCnt = sscan[2];
        double lx = sscan[3], ly = sscan[4], lw = sscan[5], lh = sscan[6];
        double lcls = sscan[7], lconfM = sscan[8], nGT = sscan[9], nCor = sscan[10];

        double msum = fmax(maskCnt, 1.0);
        double cden = fmax(totalCells + corrDen, 1.0);
        double loss_conf = 1.25 * (S0 + corrNum) / cden + lconfM / msum;
        double lx_ = lx / msum, ly_ = ly / msum, lw_ = lw / msum, lh_ = lh / msum;
        double lcls_ = (lcls / msum) / (double)nB;
        double coord = lx_ + ly_ + lw_ + lh_;
        double loss = coord + loss_conf + lcls_;
        double recall = (nGT > 0.0) ? nCor / fmax(nGT, 1.0) : 1.0;
        double precision = (nProp > 0.0) ? nCor / fmax(nProp, 1.0) : 1.0;

        out[0] = (float)loss;
        out[1] = (float)coord;
        out[2] = (float)loss_conf;
        out[3] = (float)lcls_;
        out[4] = (float)recall;
        out[5] = (float)precision;
    }
}

extern "C" void kernel_launch(void* const* d_in, const int* in_sizes, int n_in,
                              void* d_out, int out_size, void* d_ws, size_t ws_size,
                              hipStream_t stream) {
    const float* pred = (const float*)d_in[0];
    const float* tgt = (const float*)d_in[1];
    const int* tsz = (const int*)d_in[2];
    int nB = in_sizes[2];
    int T = in_sizes[1] / (nB * TCOLS);
    long long total = (long long)nB * NA * NH * NW;
    int nCells = (int)total;

    // d_ws layout: [scanPart: nB*SCAN_STRIDE floats][bgPart: NBG float2]
    float* scanPart = (float*)d_ws;
    float2* bgPart = (float2*)((char*)d_ws + (size_t)nB * SCAN_STRIDE * sizeof(float));
    float* out = (float*)d_out;

    hipLaunchKernelGGL(k_bg, dim3(NBG), dim3(256), 0, stream, pred, bgPart, nCells);
    hipLaunchKernelGGL(k_scan, dim3(nB), dim3(256), 0, stream, pred, tgt, tsz, scanPart, T);
    hipLaunchKernelGGL(k_fin, dim3(1), dim3(256), 0, stream, scanPart, bgPart, out,
                       (double)total, nB, NBG);
}

// Round 6
// 46.705 us; speedup vs baseline: 1.5689x; 1.1118x over previous
//
#include <hip/hip_runtime.h>
#include <math.h>

static constexpr int NA = 9;
static constexpr int NH = 128;
static constexpr int NW = 128;
static constexpr int NC = 4;
static constexpr int CH = 6 + NC;      // 10 channels
static constexpr int TCOLS = 13 + NC;  // 17 target columns
static constexpr float SCALE_INV = 1.0f / 16.0f;
static constexpr int NBG = 2048;       // k_bg grid
static constexpr int SCAN_STRIDE = 16; // floats per scan-block partial record

// ANCHORS_PX / 16
__constant__ float c_aw[NA] = {1.f, 2.f, 4.f, 8.f, 16.f, 2.f, 4.f, 8.f, 4.f};
__constant__ float c_ah[NA] = {1.f, 2.f, 4.f, 8.f, 16.f, 4.f, 2.f, 4.f, 8.f};

// scan partial slots: 0 corrNum, 1 corrDen, 2 maskCnt, 3 lx, 4 ly, 5 lw,
// 6 lh, 7 lcls, 8 lconfM, 9 nGT, 10 nCor
static constexpr int NSLOT = 11;

__device__ __forceinline__ float bcef(float x, float z) {
    return fmaxf(x, 0.f) - x * z + log1pf(expf(-fabsf(x)));
}
__device__ __forceinline__ float invtanh(float y) {
    if (y <= -1.f) return -2.f;
    if (y >= 1.f) return 2.f;
    return 0.5f * logf((1.f + y) / (1.f - y));
}
__device__ __forceinline__ float wredf(float v) {
#pragma unroll
    for (int o = 32; o; o >>= 1) v += __shfl_down(v, o, 64);
    return v;
}

// One block (4 waves) per batch; requires T <= TT (= 64; harness T = 50).
// All winner-resolution loops are compile-time-unrolled so the ds_bpermute
// shuffles pipeline instead of serializing on per-iteration waitcnt.
// pri = 2*t + (touch-is-best ? 1 : 0) reproduces the reference write order.
template <int TT>
__global__ __launch_bounds__(256) void k_scan(const float* __restrict__ pred,
                                              const float* __restrict__ tgt,
                                              const int* __restrict__ tsz,
                                              float* __restrict__ scanPart, int T) {
    const int b = blockIdx.x;
    const int tid = threadIdx.x;
    const int lane = tid & 63;
    const int wave = tid >> 6;

    __shared__ int sPack[64];
    __shared__ float sAccW[4][NSLOT];

    const int ts = tsz[b];
    if (tid < 64) sPack[tid] = 0;
    __syncthreads();

    float rTx = 0.f, rTy = 0.f, rTw = 0.f, rTh = 0.f;
    int rTl = 0;
    float fGT = 0.f, fCor = 0.f;

    // ---- Phase A: wave 0, lane t handles target t ----
    if (wave == 0 && lane < T) {
        const int t = lane;
        const float* row = tgt + (size_t)(b * T + t) * TCOLS;
        float gx = row[0] * SCALE_INV, gy = row[1] * SCALE_INV;
        float gh = row[3] * SCALE_INV, gw = row[4] * SCALE_INV;
        int valid = (t < ts) && (gw != 0.f) && (gh != 0.f);
        int gi = (int)gx; gi = gi < 0 ? 0 : (gi > NW - 1 ? NW - 1 : gi);
        int gj = (int)gy; gj = gj < 0 ? 0 : (gj > NH - 1 ? NH - 1 : gj);

        float bestIou = -1.f; int best = 0; int ign = 0;
#pragma unroll
        for (int a = 0; a < NA; a++) {
            float aw = c_aw[a], ah = c_ah[a];
            float inter = (fminf(gw, aw) + 1.f) * (fminf(gh, ah) + 1.f);
            float uni = (gw + 1.f) * (gh + 1.f) + (aw + 1.f) * (ah + 1.f) - inter + 1e-16f;
            float iou = inter / uni;
            if (iou > 0.5f) ign |= (1 << a);
            if (iou > bestIou) { bestIou = iou; best = a; }
        }
        sPack[t] = (valid ? 1 : 0) | (best << 1) | (ign << 5) | ((gj * NW + gi) << 14);
        rTx = invtanh(gx - ((float)gi + 0.5f));
        rTy = invtanh(gy - ((float)gj + 0.5f));
        rTw = logf(gw / c_aw[best] + 1e-16f);
        rTh = logf(gh / c_ah[best] + 1e-16f);

        float cc0 = row[13], cc1 = row[14], cc2 = row[15], cc3 = row[16];
        rTl = 0; float cmax = cc0;
        if (cc1 > cmax) { cmax = cc1; rTl = 1; }
        if (cc2 > cmax) { cmax = cc2; rTl = 2; }
        if (cc3 > cmax) { cmax = cc3; rTl = 3; }

        if (valid) {
            fGT = 1.f;
            const float* p = pred + ((((size_t)b * NA + best) * NH + gj) * NW + gi) * CH;
            float p0 = p[0];
            float px = tanhf(p[1]) + 0.5f + (float)gi;
            float py = tanhf(p[2]) + 0.5f + (float)gj;
            float pw = expf(p[5]) * c_aw[best];
            float ph = expf(p[4]) * c_ah[best];
            float b1x1 = gx - gw, b1x2 = gx + gw, b1y1 = gy - gh, b1y2 = gy + gh;
            float b2x1 = px - pw, b2x2 = px + pw, b2y1 = py - ph, b2y2 = py + ph;
            float iw = fmaxf(fminf(b1x2, b2x2) - fmaxf(b1x1, b2x1) + 1.f, 0.f);
            float ih = fmaxf(fminf(b1y2, b2y2) - fmaxf(b1y1, b2y1) + 1.f, 0.f);
            float inter = iw * ih;
            float a1 = (b1x2 - b1x1 + 1.f) * (b1y2 - b1y1 + 1.f);
            float a2 = (b2x2 - b2x1 + 1.f) * (b2y2 - b2y1 + 1.f);
            float iou = inter / (a1 + a2 - inter + 1e-16f);
            float q0 = p[6], q1 = p[7], q2 = p[8], q3 = p[9];
            int pl = 0; float qm = q0;
            if (q1 > qm) { qm = q1; pl = 1; }
            if (q2 > qm) { qm = q2; pl = 2; }
            if (q3 > qm) { qm = q3; pl = 3; }
            if (iou > 0.5f && pl == rTl && p0 > 0.f) fCor = 1.f;
        }
    }
    __syncthreads();

    const int pk = sPack[lane];   // lanes >= T hold 0 => inert in all loops

    // ---- Phase C1: winner-per-(cell,anchor) via unrolled register shuffles ----
    float corrNum = 0.f, corrDen = 0.f, lconfM = 0.f, maskCnt = 0.f;
#pragma unroll
    for (int ai = 0; ai < 3; ai++) {
        const int a = wave + 4 * ai;
        if (a >= NA) break;
        int valid = pk & 1;
        int myCell = pk >> 14;
        int myBest = (pk >> 1) & 0xF;
        int isBest = valid && (myBest == a);
        int isIgn = valid && !isBest && ((pk >> (5 + a)) & 1);
        int myPri = isBest ? (2 * lane + 1) : (isIgn ? (2 * lane) : -2);
        int maxPri = -1, anyBest = 0;
#pragma unroll
        for (int u = 0; u < TT; u++) {
            int q = __shfl(pk, u, 64);
            int same = (q & 1) && ((q >> 14) == myCell);
            int qb = (q >> 1) & 0xF;
            int qBest = same && (qb == a);
            int qIgn = same && (qb != a) && ((q >> (5 + a)) & 1);
            int pri = qBest ? (2 * u + 1) : (qIgn ? (2 * u) : -1);
            maxPri = max(maxPri, pri);
            anyBest |= qBest;
        }
        if (valid && myPri >= 0 && myPri == maxPri) {
            int gj = myCell >> 7, gi = myCell & (NW - 1);
            float conf = pred[((((size_t)b * NA + a) * NH + gj) * NW + gi) * CH];
            float bce0 = bcef(conf, 0.f);
            if (anyBest) {                    // masked: mask=1, tconf=1
                float cm = (maxPri & 1) ? 1.f : 0.f;
                float cmf = cm - 1.f;         // 0 or -1
                float bce1 = bcef(conf, 1.f);
                corrNum += bce1 * cmf - bce0;
                corrDen += cmf - 1.f;
                lconfM += bce1;
                maskCnt += 1.f;
            } else {                          // ignore-only: cmf = 0
                corrNum -= bce0;
                corrDen -= 1.f;
            }
        }
    }

    // ---- Phase C2 (wave 3 -- it has only 2 C1 anchors): last valid writer ----
    float lx = 0.f, ly = 0.f, lw = 0.f, lh = 0.f, lcls = 0.f;
    if (wave == 3) {
        int valid = pk & 1;
        int myCell = pk >> 14, myBest = (pk >> 1) & 0xF;
        int isLast = valid;
#pragma unroll
        for (int u = 0; u < TT; u++) {
            int q = __shfl(pk, u, 64);
            int later = (u > lane) && (q & 1) && ((q >> 14) == myCell) &&
                        (((q >> 1) & 0xF) == myBest);
            isLast &= !later;
        }
        if (isLast) {
            int gj = myCell >> 7, gi = myCell & (NW - 1);
            const float* pp = pred + ((((size_t)b * NA + myBest) * NH + gj) * NW + gi) * CH;
            // rT* live in wave 0's registers; re-derive from tgt row (cheap, cached)
            const float* row = tgt + (size_t)(b * T + lane) * TCOLS;
            float gx = row[0] * SCALE_INV, gy = row[1] * SCALE_INV;
            float gh_ = row[3] * SCALE_INV, gw_ = row[4] * SCALE_INV;
            float tx = invtanh(gx - ((float)gi + 0.5f));
            float ty = invtanh(gy - ((float)gj + 0.5f));
            float tw = logf(gw_ / c_aw[myBest] + 1e-16f);
            float th = logf(gh_ / c_ah[myBest] + 1e-16f);
            float cc0 = row[13], cc1 = row[14], cc2 = row[15], cc3 = row[16];
            int tl = 0; float cmax = cc0;
            if (cc1 > cmax) { cmax = cc1; tl = 1; }
            if (cc2 > cmax) { cmax = cc2; tl = 2; }
            if (cc3 > cmax) { cmax = cc3; tl = 3; }
            float dx = pp[1] - tx, dy = pp[2] - ty;
            float dw = pp[5] - tw, dh = pp[4] - th;
            lx = dx * dx; ly = dy * dy; lw = dw * dw; lh = dh * dh;
            float q0 = pp[6], q1 = pp[7], q2 = pp[8], q3 = pp[9];
            float m = fmaxf(fmaxf(q0, q1), fmaxf(q2, q3));
            float lse = m + logf(expf(q0 - m) + expf(q1 - m) + expf(q2 - m) + expf(q3 - m));
            lcls = lse - pp[6 + tl];
        }
    }

    float v;
    v = wredf(corrNum); if (lane == 0) sAccW[wave][0] = v;
    v = wredf(corrDen); if (lane == 0) sAccW[wave][1] = v;
    v = wredf(maskCnt); if (lane == 0) sAccW[wave][2] = v;
    v = wredf(lx);      if (lane == 0) sAccW[wave][3] = v;
    v = wredf(ly);      if (lane == 0) sAccW[wave][4] = v;
    v = wredf(lw);      if (lane == 0) sAccW[wave][5] = v;
    v = wredf(lh);      if (lane == 0) sAccW[wave][6] = v;
    v = wredf(lcls);    if (lane == 0) sAccW[wave][7] = v;
    v = wredf(lconfM);  if (lane == 0) sAccW[wave][8] = v;
    v = wredf(fGT);     if (lane == 0) sAccW[wave][9] = v;
    v = wredf(fCor);    if (lane == 0) sAccW[wave][10] = v;
    __syncthreads();
    if (tid < NSLOT) {
        float s = sAccW[0][tid] + sAccW[1][tid] + sAccW[2][tid] + sAccW[3][tid];
        scanPart[b * SCAN_STRIDE + tid] = s;
    }
}

// Dense background pass: nontemporal scalar gather of ONLY the conf channel
// (stride 10 floats). Every 64B line contains a conf, so line traffic equals
// a full stream with minimal instructions. One float2 partial per block.
__global__ __launch_bounds__(256) void k_bg(const float* __restrict__ pred,
                                            float2* __restrict__ bgPart, int nCells) {
    __shared__ float sdat[2][4];
    float s0 = 0.f, npos = 0.f;
    const int stride = gridDim.x * blockDim.x;
#pragma unroll 4
    for (int c = blockIdx.x * blockDim.x + threadIdx.x; c < nCells; c += stride) {
        float cv = __builtin_nontemporal_load(&pred[(size_t)c * CH]);
        s0 += fmaxf(cv, 0.f) + log1pf(expf(-fabsf(cv)));
        npos += (cv > 0.f) ? 1.f : 0.f;
    }
    s0 = wredf(s0); npos = wredf(npos);
    int wid = threadIdx.x >> 6;
    if ((threadIdx.x & 63) == 0) { sdat[0][wid] = s0; sdat[1][wid] = npos; }
    __syncthreads();
    if (threadIdx.x == 0) {
        float a0 = sdat[0][0] + sdat[0][1] + sdat[0][2] + sdat[0][3];
        float a1 = sdat[1][0] + sdat[1][1] + sdat[1][2] + sdat[1][3];
        bgPart[blockIdx.x] = make_float2(a0, a1);
    }
}

__global__ __launch_bounds__(256) void k_fin(const float* __restrict__ scanPart,
                                             const float2* __restrict__ bgPart,
                                             float* __restrict__ out,
                                             double totalCells, int nB, int nbg) {
    __shared__ double sred[2][4];
    __shared__ double sscan[NSLOT];
    const int tid = threadIdx.x;

    double s0 = 0.0, np = 0.0;
    for (int i = tid; i < nbg; i += 256) {
        float2 v = bgPart[i];
        s0 += (double)v.x; np += (double)v.y;
    }
#pragma unroll
    for (int o = 32; o; o >>= 1) {
        s0 += __shfl_down(s0, o, 64);
        np += __shfl_down(np, o, 64);
    }
    int wid = tid >> 6;
    if ((tid & 63) == 0) { sred[0][wid] = s0; sred[1][wid] = np; }
    if (tid < NSLOT) {
        double s = 0.0;
        for (int b = 0; b < nB; b++) s += (double)scanPart[b * SCAN_STRIDE + tid];
        sscan[tid] = s;
    }
    __syncthreads();
    if (tid == 0) {
        double S0 = sred[0][0] + sred[0][1] + sred[0][2] + sred[0][3];
        double nProp = sred[1][0] + sred[1][1] + sred[1][2] + sred[1][3];
        double corrNum = sscan[0], corrDen = sscan[1], maskCnt = sscan[2];
        double lx = sscan[3], ly = sscan[4], lw = sscan[5], lh = sscan[6];
        double lcls = sscan[7], lconfM = sscan[8], nGT = sscan[9], nCor = sscan[10];

        double msum = fmax(maskCnt, 1.0);
        double cden = fmax(totalCells + corrDen, 1.0);
        double loss_conf = 1.25 * (S0 + corrNum) / cden + lconfM / msum;
        double lx_ = lx / msum, ly_ = ly / msum, lw_ = lw / msum, lh_ = lh / msum;
        double lcls_ = (lcls / msum) / (double)nB;
        double coord = lx_ + ly_ + lw_ + lh_;
        double loss = coord + loss_conf + lcls_;
        double recall = (nGT > 0.0) ? nCor / fmax(nGT, 1.0) : 1.0;
        double precision = (nProp > 0.0) ? nCor / fmax(nProp, 1.0) : 1.0;

        out[0] = (float)loss;
        out[1] = (float)coord;
        out[2] = (float)loss_conf;
        out[3] = (float)lcls_;
        out[4] = (float)recall;
        out[5] = (float)precision;
    }
}

extern "C" void kernel_launch(void* const* d_in, const int* in_sizes, int n_in,
                              void* d_out, int out_size, void* d_ws, size_t ws_size,
                              hipStream_t stream) {
    const float* pred = (const float*)d_in[0];
    const float* tgt = (const float*)d_in[1];
    const int* tsz = (const int*)d_in[2];
    int nB = in_sizes[2];
    int T = in_sizes[1] / (nB * TCOLS);
    long long total = (long long)nB * NA * NH * NW;
    int nCells = (int)total;

    // d_ws layout: [scanPart: nB*SCAN_STRIDE floats][bgPart: NBG float2]
    float* scanPart = (float*)d_ws;
    float2* bgPart = (float2*)((char*)d_ws + (size_t)nB * SCAN_STRIDE * sizeof(float));
    float* out = (float*)d_out;

    hipLaunchKernelGGL(k_bg, dim3(NBG), dim3(256), 0, stream, pred, bgPart, nCells);
    hipLaunchKernelGGL(k_scan<64>, dim3(nB), dim3(256), 0, stream, pred, tgt, tsz,
                       scanPart, T);
    hipLaunchKernelGGL(k_fin, dim3(1), dim3(256), 0, stream, scanPart, bgPart, out,
                       (double)total, nB, NBG);
}

// Round 7
// 37.763 us; speedup vs baseline: 1.9404x; 1.2368x over previous
//
#include <hip/hip_runtime.h>
#include <math.h>

static constexpr int NA = 9;
static constexpr int NH = 128;
static constexpr int NW = 128;
static constexpr int NC = 4;
static constexpr int CH = 6 + NC;      // 10 channels
static constexpr int TCOLS = 13 + NC;  // 17 target columns
static constexpr float SCALE_INV = 1.0f / 16.0f;
static constexpr int NBG = 2048;       // k_bg grid
static constexpr int SCAN_STRIDE = 16; // floats per scan-block partial record
static constexpr int HSLOTS = 128;     // LDS hash table slots (>= 2*T)

// ANCHORS_PX / 16
__constant__ float c_aw[NA] = {1.f, 2.f, 4.f, 8.f, 16.f, 2.f, 4.f, 8.f, 4.f};
__constant__ float c_ah[NA] = {1.f, 2.f, 4.f, 8.f, 16.f, 4.f, 2.f, 4.f, 8.f};

// scan partial slots: 0 corrNum, 1 corrDen, 2 maskCnt, 3 lx, 4 ly, 5 lw,
// 6 lh, 7 lcls, 8 lconfM, 9 nGT, 10 nCor
static constexpr int NSLOT = 11;

__device__ __forceinline__ float bcef(float x, float z) {
    return fmaxf(x, 0.f) - x * z + log1pf(expf(-fabsf(x)));
}
__device__ __forceinline__ float invtanh(float y) {
    if (y <= -1.f) return -2.f;
    if (y >= 1.f) return 2.f;
    return 0.5f * logf((1.f + y) / (1.f - y));
}
__device__ __forceinline__ float wredf(float v) {
#pragma unroll
    for (int o = 32; o; o >>= 1) v += __shfl_down(v, o, 64);
    return v;
}

// One block (4 waves) per batch. Winner resolution via LDS hash table +
// LDS atomicMax with order-priority pri = 2*t + (best?1:0), which encodes
// the reference scan's write order exactly. Compact code, ~500 LDS atomics.
__global__ __launch_bounds__(256) void k_scan(const float* __restrict__ pred,
                                              const float* __restrict__ tgt,
                                              const int* __restrict__ tsz,
                                              float* __restrict__ scanPart, int T) {
    const int b = blockIdx.x;
    const int tid = threadIdx.x;
    const int lane = tid & 63;
    const int wave = tid >> 6;

    __shared__ int sPack[64], sTl[64], sSlot[64];
    __shared__ float sTx[64], sTy[64], sTw[64], sTh[64];
    __shared__ int sKey[HSLOTS];
    __shared__ int sPri[HSLOTS * NA];   // max over ALL touches
    __shared__ int sBest[HSLOTS * NA];  // max over BEST touches only
    __shared__ float sAccW[4][NSLOT];

    for (int i = tid; i < HSLOTS; i += 256) sKey[i] = -1;
    for (int i = tid; i < HSLOTS * NA; i += 256) { sPri[i] = -1; sBest[i] = -1; }

    const int ts = tsz[b];
    float fGT = 0.f, fCor = 0.f;

    // ---- Phase A: wave 0, lane t handles target t (T <= 64) ----
    if (wave == 0 && lane < T) {
        const int t = lane;
        const float* row = tgt + (size_t)(b * T + t) * TCOLS;
        float gx = row[0] * SCALE_INV, gy = row[1] * SCALE_INV;
        float gh = row[3] * SCALE_INV, gw = row[4] * SCALE_INV;
        int valid = (t < ts) && (gw != 0.f) && (gh != 0.f);
        int gi = (int)gx; gi = gi < 0 ? 0 : (gi > NW - 1 ? NW - 1 : gi);
        int gj = (int)gy; gj = gj < 0 ? 0 : (gj > NH - 1 ? NH - 1 : gj);

        float bestIou = -1.f; int best = 0; int ign = 0;
#pragma unroll
        for (int a = 0; a < NA; a++) {
            float aw = c_aw[a], ah = c_ah[a];
            float inter = (fminf(gw, aw) + 1.f) * (fminf(gh, ah) + 1.f);
            float uni = (gw + 1.f) * (gh + 1.f) + (aw + 1.f) * (ah + 1.f) - inter + 1e-16f;
            float iou = inter / uni;
            if (iou > 0.5f) ign |= (1 << a);
            if (iou > bestIou) { bestIou = iou; best = a; }
        }
        sPack[t] = (valid ? 1 : 0) | (best << 1) | (ign << 5) | ((gj * NW + gi) << 14);
        sTx[t] = invtanh(gx - ((float)gi + 0.5f));
        sTy[t] = invtanh(gy - ((float)gj + 0.5f));
        sTw[t] = logf(gw / c_aw[best] + 1e-16f);
        sTh[t] = logf(gh / c_ah[best] + 1e-16f);

        float cc0 = row[13], cc1 = row[14], cc2 = row[15], cc3 = row[16];
        int tl = 0; float cmax = cc0;
        if (cc1 > cmax) { cmax = cc1; tl = 1; }
        if (cc2 > cmax) { cmax = cc2; tl = 2; }
        if (cc3 > cmax) { cmax = cc3; tl = 3; }
        sTl[t] = tl;

        if (valid) {
            fGT = 1.f;
            const float* p = pred + ((((size_t)b * NA + best) * NH + gj) * NW + gi) * CH;
            float p0 = p[0];
            float px = tanhf(p[1]) + 0.5f + (float)gi;
            float py = tanhf(p[2]) + 0.5f + (float)gj;
            float pw = expf(p[5]) * c_aw[best];
            float ph = expf(p[4]) * c_ah[best];
            float b1x1 = gx - gw, b1x2 = gx + gw, b1y1 = gy - gh, b1y2 = gy + gh;
            float b2x1 = px - pw, b2x2 = px + pw, b2y1 = py - ph, b2y2 = py + ph;
            float iw = fmaxf(fminf(b1x2, b2x2) - fmaxf(b1x1, b2x1) + 1.f, 0.f);
            float ih = fmaxf(fminf(b1y2, b2y2) - fmaxf(b1y1, b2y1) + 1.f, 0.f);
            float inter = iw * ih;
            float a1 = (b1x2 - b1x1 + 1.f) * (b1y2 - b1y1 + 1.f);
            float a2 = (b2x2 - b2x1 + 1.f) * (b2y2 - b2y1 + 1.f);
            float iou = inter / (a1 + a2 - inter + 1e-16f);
            float q0 = p[6], q1 = p[7], q2 = p[8], q3 = p[9];
            int pl = 0; float qm = q0;
            if (q1 > qm) { qm = q1; pl = 1; }
            if (q2 > qm) { qm = q2; pl = 2; }
            if (q3 > qm) { qm = q3; pl = 3; }
            if (iou > 0.5f && pl == tl && p0 > 0.f) fCor = 1.f;
        }
    }
    __syncthreads();

    // ---- Insert: one thread per valid target, CAS-probe cell into table ----
    if (tid < T) {
        int p = sPack[tid];
        if (p & 1) {
            int cell = p >> 14;
            int slot = cell & (HSLOTS - 1);
            while (true) {
                int old = atomicCAS(&sKey[slot], -1, cell);
                if (old == -1 || old == cell) break;
                slot = (slot + 1) & (HSLOTS - 1);
            }
            sSlot[tid] = slot;
        }
    }
    __syncthreads();

    // ---- Touch: one thread per (t, a); priority max into table ----
    for (int item = tid; item < T * NA; item += 256) {
        int t = item / NA, a = item - t * NA;
        int p = sPack[t];
        if (!(p & 1)) continue;
        int slot = sSlot[t];
        int best = (p >> 1) & 0xF;
        if (a == best) {
            atomicMax(&sPri[slot * NA + a], 2 * t + 1);
            atomicMax(&sBest[slot * NA + a], 2 * t + 1);
        } else if ((p >> (5 + a)) & 1) {
            atomicMax(&sPri[slot * NA + a], 2 * t);
        }
    }
    __syncthreads();

    // ---- Resolve: one pass over table entries; C1 + C2 fused ----
    float corrNum = 0.f, corrDen = 0.f, lconfM = 0.f, maskCnt = 0.f;
    float lx = 0.f, ly = 0.f, lw = 0.f, lh = 0.f, lcls = 0.f;
    for (int it = tid; it < HSLOTS * NA; it += 256) {
        int slot = it / NA, a = it - slot * NA;
        int cell = sKey[slot];
        if (cell < 0) continue;
        int pm = sPri[it];
        if (pm < 0) continue;                       // (cell,a) untouched
        int bm = sBest[it];
        const float* pp = pred + ((size_t)(b * NA + a) * (NH * NW) + cell) * CH;
        float conf = pp[0];
        float bce0 = bcef(conf, 0.f);
        if (bm >= 0) {                              // masked: mask=1, tconf=1
            float cm = (float)(pm & 1);             // last-writer parity
            float cmf = cm - 1.f;                   // 0 or -1
            float bce1 = bcef(conf, 1.f);
            corrNum += bce1 * cmf - bce0;
            corrDen += cmf - 1.f;
            lconfM += bce1;
            maskCnt += 1.f;
            // C2: coords/cls from last best writer t = bm>>1
            int t = bm >> 1;
            float dx = pp[1] - sTx[t], dy = pp[2] - sTy[t];
            float dw = pp[5] - sTw[t], dh = pp[4] - sTh[t];
            lx += dx * dx; ly += dy * dy; lw += dw * dw; lh += dh * dh;
            float q0 = pp[6], q1 = pp[7], q2 = pp[8], q3 = pp[9];
            float m = fmaxf(fmaxf(q0, q1), fmaxf(q2, q3));
            float lse = m + logf(expf(q0 - m) + expf(q1 - m) + expf(q2 - m) + expf(q3 - m));
            lcls += lse - pp[6 + sTl[t]];
        } else {                                    // ignore-only: cmf = 0
            corrNum -= bce0;
            corrDen -= 1.f;
        }
    }

    float v;
    v = wredf(corrNum); if (lane == 0) sAccW[wave][0] = v;
    v = wredf(corrDen); if (lane == 0) sAccW[wave][1] = v;
    v = wredf(maskCnt); if (lane == 0) sAccW[wave][2] = v;
    v = wredf(lx);      if (lane == 0) sAccW[wave][3] = v;
    v = wredf(ly);      if (lane == 0) sAccW[wave][4] = v;
    v = wredf(lw);      if (lane == 0) sAccW[wave][5] = v;
    v = wredf(lh);      if (lane == 0) sAccW[wave][6] = v;
    v = wredf(lcls);    if (lane == 0) sAccW[wave][7] = v;
    v = wredf(lconfM);  if (lane == 0) sAccW[wave][8] = v;
    v = wredf(fGT);     if (lane == 0) sAccW[wave][9] = v;
    v = wredf(fCor);    if (lane == 0) sAccW[wave][10] = v;
    __syncthreads();
    if (tid < NSLOT) {
        float s = sAccW[0][tid] + sAccW[1][tid] + sAccW[2][tid] + sAccW[3][tid];
        scanPart[b * SCAN_STRIDE + tid] = s;
    }
}

// Dense background pass: nontemporal scalar gather of ONLY the conf channel
// (stride 10 floats). Every 64B line contains a conf, so line traffic equals
// a full stream with minimal instructions. One float2 partial per block.
__global__ __launch_bounds__(256) void k_bg(const float* __restrict__ pred,
                                            float2* __restrict__ bgPart, int nCells) {
    __shared__ float sdat[2][4];
    float s0 = 0.f, npos = 0.f;
    const int stride = gridDim.x * blockDim.x;
#pragma unroll 4
    for (int c = blockIdx.x * blockDim.x + threadIdx.x; c < nCells; c += stride) {
        float cv = __builtin_nontemporal_load(&pred[(size_t)c * CH]);
        s0 += fmaxf(cv, 0.f) + log1pf(expf(-fabsf(cv)));
        npos += (cv > 0.f) ? 1.f : 0.f;
    }
    s0 = wredf(s0); npos = wredf(npos);
    int wid = threadIdx.x >> 6;
    if ((threadIdx.x & 63) == 0) { sdat[0][wid] = s0; sdat[1][wid] = npos; }
    __syncthreads();
    if (threadIdx.x == 0) {
        float a0 = sdat[0][0] + sdat[0][1] + sdat[0][2] + sdat[0][3];
        float a1 = sdat[1][0] + sdat[1][1] + sdat[1][2] + sdat[1][3];
        bgPart[blockIdx.x] = make_float2(a0, a1);
    }
}

__global__ __launch_bounds__(256) void k_fin(const float* __restrict__ scanPart,
                                             const float2* __restrict__ bgPart,
                                             float* __restrict__ out,
                                             double totalCells, int nB, int nbg) {
    __shared__ double sred[2][4];
    __shared__ double sscan[NSLOT];
    const int tid = threadIdx.x;

    double s0 = 0.0, np = 0.0;
    for (int i = tid; i < nbg; i += 256) {
        float2 v = bgPart[i];
        s0 += (double)v.x; np += (double)v.y;
    }
#pragma unroll
    for (int o = 32; o; o >>= 1) {
        s0 += __shfl_down(s0, o, 64);
        np += __shfl_down(np, o, 64);
    }
    int wid = tid >> 6;
    if ((tid & 63) == 0) { sred[0][wid] = s0; sred[1][wid] = np; }
    if (tid < NSLOT) {
        double s = 0.0;
        for (int b = 0; b < nB; b++) s += (double)scanPart[b * SCAN_STRIDE + tid];
        sscan[tid] = s;
    }
    __syncthreads();
    if (tid == 0) {
        double S0 = sred[0][0] + sred[0][1] + sred[0][2] + sred[0][3];
        double nProp = sred[1][0] + sred[1][1] + sred[1][2] + sred[1][3];
        double corrNum = sscan[0], corrDen = sscan[1], maskCnt = sscan[2];
        double lx = sscan[3], ly = sscan[4], lw = sscan[5], lh = sscan[6];
        double lcls = sscan[7], lconfM = sscan[8], nGT = sscan[9], nCor = sscan[10];

        double msum = fmax(maskCnt, 1.0);
        double cden = fmax(totalCells + corrDen, 1.0);
        double loss_conf = 1.25 * (S0 + corrNum) / cden + lconfM / msum;
        double lx_ = lx / msum, ly_ = ly / msum, lw_ = lw / msum, lh_ = lh / msum;
        double lcls_ = (lcls / msum) / (double)nB;
        double coord = lx_ + ly_ + lw_ + lh_;
        double loss = coord + loss_conf + lcls_;
        double recall = (nGT > 0.0) ? nCor / fmax(nGT, 1.0) : 1.0;
        double precision = (nProp > 0.0) ? nCor / fmax(nProp, 1.0) : 1.0;

        out[0] = (float)loss;
        out[1] = (float)coord;
        out[2] = (float)loss_conf;
        out[3] = (float)lcls_;
        out[4] = (float)recall;
        out[5] = (float)precision;
    }
}

extern "C" void kernel_launch(void* const* d_in, const int* in_sizes, int n_in,
                              void* d_out, int out_size, void* d_ws, size_t ws_size,
                              hipStream_t stream) {
    const float* pred = (const float*)d_in[0];
    const float* tgt = (const float*)d_in[1];
    const int* tsz = (const int*)d_in[2];
    int nB = in_sizes[2];
    int T = in_sizes[1] / (nB * TCOLS);
    long long total = (long long)nB * NA * NH * NW;
    int nCells = (int)total;

    // d_ws layout: [scanPart: nB*SCAN_STRIDE floats][bgPart: NBG float2]
    float* scanPart = (float*)d_ws;
    float2* bgPart = (float2*)((char*)d_ws + (size_t)nB * SCAN_STRIDE * sizeof(float));
    float* out = (float*)d_out;

    hipLaunchKernelGGL(k_bg, dim3(NBG), dim3(256), 0, stream, pred, bgPart, nCells);
    hipLaunchKernelGGL(k_scan, dim3(nB), dim3(256), 0, stream, pred, tgt, tsz,
                       scanPart, T);
    hipLaunchKernelGGL(k_fin, dim3(1), dim3(256), 0, stream, scanPart, bgPart, out,
                       (double)total, nB, NBG);
}